// Round 11
// baseline (31.984 us; speedup 1.0000x reference)
//
#include <hip/hip_runtime.h>
#include <hip/hip_bf16.h>
#include <math.h>

// SRNLayer: B=4, C=3, H=W=96, K=5, PAD=2, S=2, O=32, DEG=4
// n = 75 (padded 96), P = 9, L = 36864.
// err = (u - q)/(75*var); q = s1^2/75 + ||G'_o y||^2, G' drops the p=0 row
// (== ones/sqrt(75)) -> 256 rows = 16 MFMA tiles (tile t = o's {2t,2t+1}).
// R11: MEASUREMENT ROUND. Identical kernels to R10; srn_main launched TWICE
// (idempotent, deterministic). main_true = dur_R11 - dur_R10 cleanly splits
// "kernel-bound" (Delta >= 10us) from "dispatch-floor-bound" (Delta <= 5us).

typedef __attribute__((ext_vector_type(8))) short bf16x8;
typedef __attribute__((ext_vector_type(4))) float f32x4;
typedef __attribute__((ext_vector_type(4))) int i32x4;

#define TRI(p, q) ((p) * ((p) + 1) / 2 + (q))

__global__ __launch_bounds__(96) void srn_setup(const float* __restrict__ Wt,
                                                __hip_bfloat16* __restrict__ Gb) {
  const int o = blockIdx.x;  // 0..31
  __shared__ double Xf[96][9];
  __shared__ double Cm[9][9];
  __shared__ double Rf[45];  // Cholesky factor, diag as reciprocal
  __shared__ double scs[9];
  const int tid = threadIdx.x;
  if (tid < 75) {
    double x0 = (double)Wt[o * 150 + tid * 2 + 0];
    double x1 = (double)Wt[o * 150 + tid * 2 + 1];
    Xf[tid][0] = 1.0;
    double p = x0;
    Xf[tid][1] = p; p *= x0; Xf[tid][2] = p; p *= x0; Xf[tid][3] = p; p *= x0; Xf[tid][4] = p;
    p = x1;
    Xf[tid][5] = p; p *= x1; Xf[tid][6] = p; p *= x1; Xf[tid][7] = p; p *= x1; Xf[tid][8] = p;
  }
  __syncthreads();
  if (tid < 81) {
    const int p = tid / 9, q = tid - (tid / 9) * 9;
    double s = 0.0;
#pragma unroll
    for (int n = 0; n < 75; n++) s += Xf[n][p] * Xf[n][q];
    Cm[p][q] = s;
  }
  __syncthreads();
  if (tid == 0) {
    double sc[9];
#pragma unroll
    for (int p = 0; p < 9; p++) sc[p] = 1.0 / sqrt(Cm[p][p]);
    double A[45];
#pragma unroll
    for (int p = 0; p < 9; p++)
#pragma unroll
      for (int q = 0; q <= p; q++) A[TRI(p, q)] = Cm[p][q] * sc[p] * sc[q];
#pragma unroll
    for (int p = 0; p < 9; p++) {
      double s = A[TRI(p, p)];
#pragma unroll
      for (int i = 0; i < p; i++) s -= A[TRI(p, i)] * A[TRI(p, i)];
      const double rp = sqrt(s);
      A[TRI(p, p)] = rp;
      const double ir = 1.0 / rp;
#pragma unroll
      for (int r = p + 1; r < 9; r++) {
        double t = A[TRI(r, p)];
#pragma unroll
        for (int i = 0; i < p; i++) t -= A[TRI(r, i)] * A[TRI(p, i)];
        A[TRI(r, p)] = t * ir;
      }
    }
#pragma unroll
    for (int k = 0; k < 45; k++) Rf[k] = A[k];
#pragma unroll
    for (int p = 0; p < 9; p++) Rf[TRI(p, p)] = 1.0 / A[TRI(p, p)];
#pragma unroll
    for (int p = 0; p < 9; p++) scs[p] = sc[p];
  }
  __syncthreads();
  if (tid < 96) {
    double z[9];
    if (tid < 75) {
#pragma unroll
      for (int p = 0; p < 9; p++) {
        double s = scs[p] * Xf[tid][p];
#pragma unroll
        for (int i = 0; i < p; i++) s -= Rf[TRI(p, i)] * z[i];
        z[p] = s * Rf[TRI(p, p)];
      }
    } else {
#pragma unroll
      for (int p = 0; p < 9; p++) z[p] = 0.0;
    }
    // fragment-order store: tile t=o>>1, row m16=(o&1)*8+(p-1),
    // chunk ch=n>>5, g4=(n>>3)&3, j=n&7; lane = m16 + 16*g4.
    const int t = o >> 1;
    const int ch = tid >> 5;
    const int g4r = (tid >> 3) & 3;
    const int j = tid & 7;
    const int base = ((t * 3 + ch) << 9) + ((o & 1) << 6) + (g4r << 7) + j;
#pragma unroll
    for (int p = 1; p < 9; p++)
      Gb[base + ((p - 1) << 3)] = __float2bfloat16((float)z[p]);
  }
}

__global__ __launch_bounds__(512, 2) void srn_main(const float* __restrict__ y2,
                                                   const __hip_bfloat16* __restrict__ Gbh,
                                                   float* __restrict__ out) {
  __shared__ __attribute__((aligned(16))) short Gs[24576];  // 48 KB: full G
  __shared__ int tab[96];

  const int tid = threadIdx.x;

  // ---- k -> (c,di,dj) offset table ----
  if (tid < 96) {
    const int c = (tid * 41) >> 10;   // k/25 for k<96
    const int r = tid - c * 25;
    const int di = (r * 52) >> 8;     // r/5 for r<25
    const int dj = r - di * 5;
    tab[tid] = (di << 20) | (dj << 16) | (c * 9216 + di * 96 + dj);
  }

  // ---- stage all of G into LDS (coalesced: 6 x dwordx4 per thread) ----
  {
    const i32x4* gsrc = (const i32x4*)Gbh;
    i32x4* gdst = (i32x4*)Gs;
#pragma unroll
    for (int k = 0; k < 6; k++) gdst[k * 512 + tid] = gsrc[k * 512 + tid];
  }
  __syncthreads();

  const int lane = tid & 63;
  const int wv = tid >> 6;       // 0..7
  const int m16 = lane & 15, g4 = lane >> 4;
  const int rb = wv >> 2;        // o-half 0/1
  const int tau2 = blockIdx.x * 4 + (wv & 3);  // 0..2303 position-tile
  const int b = tau2 / 576;
  const int rem = tau2 - b * 576;
  const int h = rem / 6;
  const int w0 = (rem - h * 6) * 16;
  const int w = w0 + m16;
  const int l = h * 96 + w;

  i32x4 e[6];
  const i32x4* tb = (const i32x4*)tab;
#pragma unroll
  for (int ch = 0; ch < 3; ch++) {
    e[ch * 2 + 0] = tb[ch * 8 + g4 * 2 + 0];
    e[ch * 2 + 1] = tb[ch * 8 + g4 * 2 + 1];
  }

  // ---- gather the 24 unfold values for this lane's B fragments ----
  const float* yb = y2 + b * 27648;
  const bool fast = ((unsigned)(h - 2) < 92u) && (w0 >= 16) && (w0 <= 64);
  const int live1 = 11 - g4 * 8;  // #live j in chunk 2
  float vv[24];
  if (fast) {
    const float* yl = yb + (l - 194);
#pragma unroll
    for (int ch = 0; ch < 3; ch++)
#pragma unroll
      for (int j = 0; j < 8; j++) {
        const int ent = (j < 4) ? e[ch * 2][j] : e[ch * 2 + 1][j - 4];
        float v = 0.f;
        if (ch < 2 || j < live1) v = yl[ent & 0xFFFF];
        vv[ch * 8 + j] = v;
      }
  } else {
#pragma unroll
    for (int ch = 0; ch < 3; ch++)
#pragma unroll
      for (int j = 0; j < 8; j++) {
        const int ent = (j < 4) ? e[ch * 2][j] : e[ch * 2 + 1][j - 4];
        float v = 0.f;
        if (ch < 2 || j < live1) {
          const int di = ent >> 20, dj = (ent >> 16) & 15;
          const int off = ent & 0xFFFF;
          const int c9216 = off - di * 96 - dj;
          const int hh = h + di - 2, ww = w + dj - 2;
          const float m = (((unsigned)hh < 96u) && ((unsigned)ww < 96u)) ? 1.f : 0.f;
          v = yb[c9216 + min(max(hh, 0), 95) * 96 + min(max(ww, 0), 95)] * m;
        }
        vv[ch * 8 + j] = v;
      }
  }

  // ---- bf16 fragments + in-fragment stats ----
  bf16x8 Bf[3];
  float up = 0.f, sp = 0.f;
#pragma unroll
  for (int ch = 0; ch < 3; ch++)
#pragma unroll
    for (int j = 0; j < 8; j++) {
      const __hip_bfloat16 hb = __float2bfloat16(vv[ch * 8 + j]);  // RNE
      const float vr = __bfloat162float(hb);
      sp += vr;
      up = fmaf(vr, vr, up);
      Bf[ch][j] = *reinterpret_cast<const short*>(&hb);
    }
  up += __shfl_xor(up, 16); up += __shfl_xor(up, 32);
  sp += __shfl_xor(sp, 16); sp += __shfl_xor(sp, 32);

  const float qbase = sp * sp * (1.f / 75.f);
  const float var = (up - qbase) * (1.f / 74.f);
  const float cerr = 1.f / (75.f * var);
  const float e1 = 0.36787944117144233f;
  const float r1 = 1.f / (1.f - e1);
  const float c2 = e1 * r1 + 0.5f;

  // ---- 8 MFMA tiles: A from LDS (conflict-free ds_read_b128) ----
  const short* Ab = Gs + rb * 12288 + lane * 8;
  float* ob = out + b * 294912 + (rb * 16 + (g4 >> 1)) * 9216 + l;
  const f32x4 z = {0.f, 0.f, 0.f, 0.f};
#pragma unroll
  for (int t = 0; t < 8; t++) {
    const short* At = Ab + t * 1536;  // 3 chunks x 512 shorts
    const bf16x8 A0 = *(const bf16x8*)(At);
    const bf16x8 A1 = *(const bf16x8*)(At + 512);
    const bf16x8 A2 = *(const bf16x8*)(At + 1024);
    f32x4 acc = z;
    acc = __builtin_amdgcn_mfma_f32_16x16x32_bf16(A0, Bf[0], acc, 0, 0, 0);
    acc = __builtin_amdgcn_mfma_f32_16x16x32_bf16(A1, Bf[1], acc, 0, 0, 0);
    acc = __builtin_amdgcn_mfma_f32_16x16x32_bf16(A2, Bf[2], acc, 0, 0, 0);
    float qp = acc[0] * acc[0];
    qp = fmaf(acc[1], acc[1], qp);
    qp = fmaf(acc[2], acc[2], qp);
    qp = fmaf(acc[3], acc[3], qp);
    qp += __shfl_xor(qp, 16);  // sum g4-pair -> q for this lane's o
    const float q = qp + qbase;
    const float err = (up - q) * cerr;
    const float a = fmaf(__expf(-err), r1, -c2);
    if ((g4 & 1) == 0) ob[t * 18432] = a;  // g4=0 -> o=2t, g4=2 -> o=2t+1
  }
}

extern "C" void kernel_launch(void* const* d_in, const int* in_sizes, int n_in,
                              void* d_out, int out_size, void* d_ws, size_t ws_size,
                              hipStream_t stream) {
  const float* y2 = (const float*)d_in[0];
  const float* Wt = (const float*)d_in[1];
  float* out = (float*)d_out;
  __hip_bfloat16* Gb = (__hip_bfloat16*)d_ws;  // 16*3*64*8*2 = 49,152 B

  srn_setup<<<32, 96, 0, stream>>>(Wt, Gb);
  // MEASUREMENT: main launched twice (idempotent — identical output values).
  // main_true_duration = dur_us(R11) - dur_us(R10).
  srn_main<<<576, 512, 0, stream>>>(y2, Gb, out);
  srn_main<<<576, 512, 0, stream>>>(y2, Gb, out);
}

// Round 12
// 20.770 us; speedup vs baseline: 1.5399x; 1.5399x over previous
//
#include <hip/hip_runtime.h>
#include <hip/hip_bf16.h>
#include <math.h>

// SRNLayer: B=4, C=3, H=W=96, K=5, PAD=2, S=2, O=32, DEG=4
// n = 75 (padded 96), P = 9, L = 36864.
// err = (u - q)/(75*var); q = s1^2/75 + ||G'_o y||^2, G' drops the p=0 row
// (== ones/sqrt(75)) -> 256 rows = 16 MFMA tiles (tile t = o's {2t,2t+1}).
// R12: ONE wave per position-tile does ALL 16 o-tiles (R5-R11 gathered each
// position twice, once per o-half). Gather/stats phases 4608 -> 2304, G
// staging 576 -> 288 blocks. MFMA/ds_read totals unchanged. R11 established
// main_true ~= 10.1 us and a ~10 us fixed replay floor (likely clock-sagged).

typedef __attribute__((ext_vector_type(8))) short bf16x8;
typedef __attribute__((ext_vector_type(4))) float f32x4;
typedef __attribute__((ext_vector_type(4))) int i32x4;

#define TRI(p, q) ((p) * ((p) + 1) / 2 + (q))

__global__ __launch_bounds__(96) void srn_setup(const float* __restrict__ Wt,
                                                __hip_bfloat16* __restrict__ Gb) {
  const int o = blockIdx.x;  // 0..31
  __shared__ double Xf[96][9];
  __shared__ double Cm[9][9];
  __shared__ double Rf[45];  // Cholesky factor, diag as reciprocal
  __shared__ double scs[9];
  const int tid = threadIdx.x;
  if (tid < 75) {
    double x0 = (double)Wt[o * 150 + tid * 2 + 0];
    double x1 = (double)Wt[o * 150 + tid * 2 + 1];
    Xf[tid][0] = 1.0;
    double p = x0;
    Xf[tid][1] = p; p *= x0; Xf[tid][2] = p; p *= x0; Xf[tid][3] = p; p *= x0; Xf[tid][4] = p;
    p = x1;
    Xf[tid][5] = p; p *= x1; Xf[tid][6] = p; p *= x1; Xf[tid][7] = p; p *= x1; Xf[tid][8] = p;
  }
  __syncthreads();
  if (tid < 81) {
    const int p = tid / 9, q = tid - (tid / 9) * 9;
    double s = 0.0;
#pragma unroll
    for (int n = 0; n < 75; n++) s += Xf[n][p] * Xf[n][q];
    Cm[p][q] = s;
  }
  __syncthreads();
  if (tid == 0) {
    double sc[9];
#pragma unroll
    for (int p = 0; p < 9; p++) sc[p] = 1.0 / sqrt(Cm[p][p]);
    double A[45];
#pragma unroll
    for (int p = 0; p < 9; p++)
#pragma unroll
      for (int q = 0; q <= p; q++) A[TRI(p, q)] = Cm[p][q] * sc[p] * sc[q];
#pragma unroll
    for (int p = 0; p < 9; p++) {
      double s = A[TRI(p, p)];
#pragma unroll
      for (int i = 0; i < p; i++) s -= A[TRI(p, i)] * A[TRI(p, i)];
      const double rp = sqrt(s);
      A[TRI(p, p)] = rp;
      const double ir = 1.0 / rp;
#pragma unroll
      for (int r = p + 1; r < 9; r++) {
        double t = A[TRI(r, p)];
#pragma unroll
        for (int i = 0; i < p; i++) t -= A[TRI(r, i)] * A[TRI(p, i)];
        A[TRI(r, p)] = t * ir;
      }
    }
#pragma unroll
    for (int k = 0; k < 45; k++) Rf[k] = A[k];
#pragma unroll
    for (int p = 0; p < 9; p++) Rf[TRI(p, p)] = 1.0 / A[TRI(p, p)];
#pragma unroll
    for (int p = 0; p < 9; p++) scs[p] = sc[p];
  }
  __syncthreads();
  if (tid < 96) {
    double z[9];
    if (tid < 75) {
#pragma unroll
      for (int p = 0; p < 9; p++) {
        double s = scs[p] * Xf[tid][p];
#pragma unroll
        for (int i = 0; i < p; i++) s -= Rf[TRI(p, i)] * z[i];
        z[p] = s * Rf[TRI(p, p)];
      }
    } else {
#pragma unroll
      for (int p = 0; p < 9; p++) z[p] = 0.0;
    }
    // fragment-order store: tile t=o>>1, row m16=(o&1)*8+(p-1),
    // chunk ch=n>>5, g4=(n>>3)&3, j=n&7; lane = m16 + 16*g4.
    const int t = o >> 1;
    const int ch = tid >> 5;
    const int g4r = (tid >> 3) & 3;
    const int j = tid & 7;
    const int base = ((t * 3 + ch) << 9) + ((o & 1) << 6) + (g4r << 7) + j;
#pragma unroll
    for (int p = 1; p < 9; p++)
      Gb[base + ((p - 1) << 3)] = __float2bfloat16((float)z[p]);
  }
}

__global__ __launch_bounds__(512, 2) void srn_main(const float* __restrict__ y2,
                                                   const __hip_bfloat16* __restrict__ Gbh,
                                                   float* __restrict__ out) {
  __shared__ __attribute__((aligned(16))) short Gs[24576];  // 48 KB: full G
  __shared__ int tab[96];

  const int tid = threadIdx.x;

  // ---- k -> (c,di,dj) offset table ----
  if (tid < 96) {
    const int c = (tid * 41) >> 10;   // k/25 for k<96
    const int r = tid - c * 25;
    const int di = (r * 52) >> 8;     // r/5 for r<25
    const int dj = r - di * 5;
    tab[tid] = (di << 20) | (dj << 16) | (c * 9216 + di * 96 + dj);
  }

  // ---- stage all of G into LDS (coalesced: 6 x dwordx4 per thread) ----
  {
    const i32x4* gsrc = (const i32x4*)Gbh;
    i32x4* gdst = (i32x4*)Gs;
#pragma unroll
    for (int k = 0; k < 6; k++) gdst[k * 512 + tid] = gsrc[k * 512 + tid];
  }
  __syncthreads();

  const int lane = tid & 63;
  const int wv = tid >> 6;       // 0..7
  const int m16 = lane & 15, g4 = lane >> 4;
  const int tau2 = blockIdx.x * 8 + wv;  // 0..2303 position-tile
  const int b = tau2 / 576;
  const int rem = tau2 - b * 576;
  const int h = rem / 6;
  const int w0 = (rem - h * 6) * 16;
  const int w = w0 + m16;
  const int l = h * 96 + w;

  i32x4 e[6];
  const i32x4* tb = (const i32x4*)tab;
#pragma unroll
  for (int ch = 0; ch < 3; ch++) {
    e[ch * 2 + 0] = tb[ch * 8 + g4 * 2 + 0];
    e[ch * 2 + 1] = tb[ch * 8 + g4 * 2 + 1];
  }

  // ---- gather the 24 unfold values for this lane's B fragments ----
  const float* yb = y2 + b * 27648;
  const bool fast = ((unsigned)(h - 2) < 92u) && (w0 >= 16) && (w0 <= 64);
  const int live1 = 11 - g4 * 8;  // #live j in chunk 2
  float vv[24];
  if (fast) {
    const float* yl = yb + (l - 194);
#pragma unroll
    for (int ch = 0; ch < 3; ch++)
#pragma unroll
      for (int j = 0; j < 8; j++) {
        const int ent = (j < 4) ? e[ch * 2][j] : e[ch * 2 + 1][j - 4];
        float v = 0.f;
        if (ch < 2 || j < live1) v = yl[ent & 0xFFFF];
        vv[ch * 8 + j] = v;
      }
  } else {
#pragma unroll
    for (int ch = 0; ch < 3; ch++)
#pragma unroll
      for (int j = 0; j < 8; j++) {
        const int ent = (j < 4) ? e[ch * 2][j] : e[ch * 2 + 1][j - 4];
        float v = 0.f;
        if (ch < 2 || j < live1) {
          const int di = ent >> 20, dj = (ent >> 16) & 15;
          const int off = ent & 0xFFFF;
          const int c9216 = off - di * 96 - dj;
          const int hh = h + di - 2, ww = w + dj - 2;
          const float m = (((unsigned)hh < 96u) && ((unsigned)ww < 96u)) ? 1.f : 0.f;
          v = yb[c9216 + min(max(hh, 0), 95) * 96 + min(max(ww, 0), 95)] * m;
        }
        vv[ch * 8 + j] = v;
      }
  }

  // ---- bf16 fragments + in-fragment stats ----
  bf16x8 Bf[3];
  float up = 0.f, sp = 0.f;
#pragma unroll
  for (int ch = 0; ch < 3; ch++)
#pragma unroll
    for (int j = 0; j < 8; j++) {
      const __hip_bfloat16 hb = __float2bfloat16(vv[ch * 8 + j]);  // RNE
      const float vr = __bfloat162float(hb);
      sp += vr;
      up = fmaf(vr, vr, up);
      Bf[ch][j] = *reinterpret_cast<const short*>(&hb);
    }
  up += __shfl_xor(up, 16); up += __shfl_xor(up, 32);
  sp += __shfl_xor(sp, 16); sp += __shfl_xor(sp, 32);

  const float qbase = sp * sp * (1.f / 75.f);
  const float var = (up - qbase) * (1.f / 74.f);
  const float cerr = 1.f / (75.f * var);
  const float e1 = 0.36787944117144233f;
  const float r1 = 1.f / (1.f - e1);
  const float c2 = e1 * r1 + 0.5f;

  // ---- all 16 MFMA tiles (o = 2t + (g4>>1)); A from LDS ds_read_b128 ----
  const short* Ab = Gs + lane * 8;
  float* ob = out + b * 294912 + l;
  const f32x4 z = {0.f, 0.f, 0.f, 0.f};
#pragma unroll
  for (int t = 0; t < 16; t++) {
    const short* At = Ab + t * 1536;  // 3 chunks x 512 shorts
    const bf16x8 A0 = *(const bf16x8*)(At);
    const bf16x8 A1 = *(const bf16x8*)(At + 512);
    const bf16x8 A2 = *(const bf16x8*)(At + 1024);
    f32x4 acc = z;
    acc = __builtin_amdgcn_mfma_f32_16x16x32_bf16(A0, Bf[0], acc, 0, 0, 0);
    acc = __builtin_amdgcn_mfma_f32_16x16x32_bf16(A1, Bf[1], acc, 0, 0, 0);
    acc = __builtin_amdgcn_mfma_f32_16x16x32_bf16(A2, Bf[2], acc, 0, 0, 0);
    float qp = acc[0] * acc[0];
    qp = fmaf(acc[1], acc[1], qp);
    qp = fmaf(acc[2], acc[2], qp);
    qp = fmaf(acc[3], acc[3], qp);
    qp += __shfl_xor(qp, 16);  // sum g4-pair -> q for this lane's o
    const float q = qp + qbase;
    const float err = (up - q) * cerr;
    const float a = fmaf(__expf(-err), r1, -c2);
    if ((g4 & 1) == 0) ob[(2 * t + (g4 >> 1)) * 9216] = a;
  }
}

extern "C" void kernel_launch(void* const* d_in, const int* in_sizes, int n_in,
                              void* d_out, int out_size, void* d_ws, size_t ws_size,
                              hipStream_t stream) {
  const float* y2 = (const float*)d_in[0];
  const float* Wt = (const float*)d_in[1];
  float* out = (float*)d_out;
  __hip_bfloat16* Gb = (__hip_bfloat16*)d_ws;  // 16*3*64*8*2 = 49,152 B

  srn_setup<<<32, 96, 0, stream>>>(Wt, Gb);
  srn_main<<<288, 512, 0, stream>>>(y2, Gb, out);
}